// Round 2
// baseline (79.448 us; speedup 1.0000x reference)
//
#include <hip/hip_runtime.h>
#include <hip/hip_bf16.h>

// out[b,s,c] = x[b,s,:] @ W, W[r][c] = kernel[(r%512)*4096 + c]
// xr[m][r'] = sum_{i<8} x[m][r'+512i]  (M=8192, K'=512); out = xr @ kernel-matrix
// GEMM: 256x256 tile, 8 waves (2x4), BK=32, 3-buffer LDS pipeline with counted
// vmcnt (never 0 in steady state), both-sides XOR swizzle, setprio, XCD swizzle.

#define M_TOT   8192
#define N_TOT   4096
#define K_RED   512
#define K_FULL  4096
#define NSTEP   16          // K_RED / 32

typedef __attribute__((ext_vector_type(8))) short bf16x8;
typedef __attribute__((ext_vector_type(4))) float f32x4;
typedef __attribute__((ext_vector_type(4))) unsigned short u16x4;

static __device__ __forceinline__ unsigned short f2bf(float f) {
    unsigned int u = __float_as_uint(f);
    unsigned int r = (u + 0x7fffu + ((u >> 16) & 1u)) >> 16;
    return (unsigned short)r;
}

// ---------------------------------------------------------------------------
// Prep kernel (fused): blocks [0,4096) do the 8-way reduce of x -> xr (bf16);
// blocks [4096,4608) transpose+cast kernel -> bt[c][r'].
// ---------------------------------------------------------------------------
__global__ __launch_bounds__(256) void prep(const float* __restrict__ x,
                                            const int* __restrict__ kin,
                                            unsigned short* __restrict__ xr,
                                            unsigned short* __restrict__ bt) {
    __shared__ unsigned short tile[64][65];
    if (blockIdx.x < 4096) {
        const int row = blockIdx.x * 2 + (threadIdx.x >> 7);
        const int t2  = threadIdx.x & 127;
        const float* xp = x + (size_t)row * K_FULL + t2 * 4;
        float a0 = 0.f, a1 = 0.f, a2 = 0.f, a3 = 0.f;
#pragma unroll
        for (int i = 0; i < 8; ++i) {
            float4 v = *reinterpret_cast<const float4*>(xp + (size_t)i * K_RED);
            a0 += v.x; a1 += v.y; a2 += v.z; a3 += v.w;
        }
        u16x4 o;
        o.x = f2bf(a0); o.y = f2bf(a1); o.z = f2bf(a2); o.w = f2bf(a3);
        *reinterpret_cast<u16x4*>(xr + (size_t)row * K_RED + t2 * 4) = o;
    } else {
        const int b  = blockIdx.x - 4096;        // 0..511
        const int c0 = (b & 63) * 64;
        const int r0 = (b >> 6) * 64;
        const int tx = threadIdx.x & 63;
        const int ty = threadIdx.x >> 6;         // 0..3
#pragma unroll
        for (int rr = 0; rr < 64; rr += 4) {
            int r = r0 + rr + ty;
            tile[rr + ty][tx] = f2bf((float)kin[(size_t)r * N_TOT + c0 + tx]);
        }
        __syncthreads();
#pragma unroll
        for (int cc = 0; cc < 64; cc += 4) {
            int c = c0 + cc + ty;
            bt[(size_t)c * K_RED + r0 + tx] = tile[tx][cc + ty];
        }
    }
}

// ---------------------------------------------------------------------------
// GEMM: C[8192][4096] f32 = A[8192][512] bf16 @ Bt[4096][512]^T
// 256x256 tile, 512 threads = 8 waves (2 Mx4 N), per-wave 128x64 output.
// BK=32, 3 LDS buffers x (A 16KB + B 16KB) = 96KB.
// Swizzle: byte ^= ((row&3)<<4) within each 64B row (both stage-src and read).
// ---------------------------------------------------------------------------
__global__ __launch_bounds__(512, 2) void gemm512(const unsigned short* __restrict__ A,
                                                  const unsigned short* __restrict__ Bt,
                                                  float* __restrict__ C) {
    __shared__ char smem[3 * 32768];

    const int tid  = threadIdx.x;
    const int lane = tid & 63;
    const int w    = tid >> 6;        // 0..7
    const int wr   = w >> 2;          // 0..1  (M half)
    const int wc   = w & 3;           // 0..3  (N quarter)
    const int l15  = lane & 15;
    const int lhi  = lane >> 4;       // 0..3

    // XCD-aware bijective swizzle: 512 blocks, 512 % 8 == 0
    const int wg  = blockIdx.x;
    const int swz = (wg & 7) * 64 + (wg >> 3);
    const int m0  = (swz >> 4) * 256;    // 32 m-blocks
    const int n0  = (swz & 15) * 256;    // 16 n-blocks

    // Stage one BK=32 K-slice of A (16KB) + B (16KB) into buffer `buf`.
    // LDS dest is LINEAR (global_load_lds requirement); the global source is
    // pre-swizzled with the same involution the reads apply (rule #21).
    auto stage = [&](int buf, int t) {
        const int sb = buf * 32768;
#pragma unroll
        for (int it = 0; it < 2; ++it) {
            const int lb   = (it * 512 + tid) * 16;       // byte in 16KB tile
            const int row  = lb >> 6;                     // 64B per row (32 k * 2B)
            const int scol = (lb ^ ((row & 3) << 4)) & 63;
            const char* ga = (const char*)A  + (size_t)(m0 + row) * (K_RED * 2) + t * 64 + scol;
            const char* gb = (const char*)Bt + (size_t)(n0 + row) * (K_RED * 2) + t * 64 + scol;
            __builtin_amdgcn_global_load_lds(
                (__attribute__((address_space(1))) void*)ga,
                (__attribute__((address_space(3))) void*)(smem + sb + lb), 16, 0, 0);
            __builtin_amdgcn_global_load_lds(
                (__attribute__((address_space(1))) void*)gb,
                (__attribute__((address_space(3))) void*)(smem + sb + 16384 + lb), 16, 0, 0);
        }
    };

    // Read offsets (swizzled). row&3 == l15&3 for all fragments (16-row tiles).
    const int swr = (l15 & 3) << 4;
    int offA[8], offB[4];
#pragma unroll
    for (int mi = 0; mi < 8; ++mi)
        offA[mi] = ((wr * 128 + mi * 16 + l15) << 6) + ((lhi << 4) ^ swr);
#pragma unroll
    for (int ni = 0; ni < 4; ++ni)
        offB[ni] = 16384 + ((wc * 64 + ni * 16 + l15) << 6) + ((lhi << 4) ^ swr);

    f32x4 acc[8][4] = {};

    // Prologue: steps 0 and 1 in flight; retire step 0, keep step 1 flying.
    stage(0, 0);
    stage(1, 1);
    asm volatile("s_waitcnt vmcnt(4)" ::: "memory");
    __builtin_amdgcn_s_barrier();
    asm volatile("" ::: "memory");

    int cur = 0;
    for (int t = 0; t < NSTEP; ++t) {
        if (t <= NSTEP - 3) {
            int nn = cur + 2; if (nn >= 3) nn -= 3;
            stage(nn, t + 2);            // buffer retired at step t-1's barrier
        }
        asm volatile("" ::: "memory");
        const int sb = cur * 32768;
        bf16x8 af[8], bfr[4];
#pragma unroll
        for (int mi = 0; mi < 8; ++mi)
            af[mi] = *reinterpret_cast<const bf16x8*>(smem + sb + offA[mi]);
#pragma unroll
        for (int ni = 0; ni < 4; ++ni)
            bfr[ni] = *reinterpret_cast<const bf16x8*>(smem + sb + offB[ni]);
        __builtin_amdgcn_s_setprio(1);
#pragma unroll
        for (int mi = 0; mi < 8; ++mi)
#pragma unroll
            for (int ni = 0; ni < 4; ++ni)
                acc[mi][ni] = __builtin_amdgcn_mfma_f32_16x16x32_bf16(
                    af[mi], bfr[ni], acc[mi][ni], 0, 0, 0);
        __builtin_amdgcn_s_setprio(0);
        asm volatile("" ::: "memory");
        // Retire step t+1's loads; keep step t+2's in flight (never vmcnt(0)
        // in steady state). Tail: t==14 has only step-15 loads outstanding.
        if (t <= NSTEP - 3)       asm volatile("s_waitcnt vmcnt(4)" ::: "memory");
        else if (t == NSTEP - 2)  asm volatile("s_waitcnt vmcnt(0)" ::: "memory");
        if (t <= NSTEP - 2) {
            __builtin_amdgcn_s_barrier();
            asm volatile("" ::: "memory");
        }
        cur += 1; if (cur == 3) cur = 0;
    }

    // Epilogue: C/D layout col = lane&15, row = (lane>>4)*4 + reg
#pragma unroll
    for (int mi = 0; mi < 8; ++mi) {
#pragma unroll
        for (int ni = 0; ni < 4; ++ni) {
            f32x4 v = acc[mi][ni];
            const int    col = n0 + wc * 64 + ni * 16 + l15;
            const size_t rb  = m0 + wr * 128 + mi * 16 + lhi * 4;
#pragma unroll
            for (int r = 0; r < 4; ++r)
                C[(rb + r) * N_TOT + col] = v[r];
        }
    }
}

// ---------------------------------------------------------------------------
extern "C" void kernel_launch(void* const* d_in, const int* in_sizes, int n_in,
                              void* d_out, int out_size, void* d_ws, size_t ws_size,
                              hipStream_t stream) {
    const float* x   = (const float*)d_in[0];       // [2,4096,4096] f32
    const int*   kin = (const int*)d_in[1];         // [2097152] int32 in {-1,0,1}
    float*       out = (float*)d_out;               // [2,4096,4096] f32

    unsigned short* xr = (unsigned short*)d_ws;                                    // 8 MB
    unsigned short* bt = (unsigned short*)((char*)d_ws + (size_t)M_TOT * K_RED * 2); // 4 MB

    prep<<<dim3(4096 + 512), 256, 0, stream>>>(x, kin, xr, bt);
    gemm512<<<dim3((M_TOT / 256) * (N_TOT / 256)), 512, 0, stream>>>(xr, bt, out);
}